// Round 6
// baseline (1744.848 us; speedup 1.0000x reference)
//
#include <hip/hip_runtime.h>
#include <hip/hip_bf16.h>

// DecoderRNN: attention degenerate (enc seq len == 1 -> awe == gate*features).
// R6: recurrence restructured to ONE grid barrier per step among EIGHT blocks:
//     each block redundantly computes full beta/awe (cheap MFMA) so only h is
//     exchanged; h double-buffered (x0/x1) -> no read/write race; h staged to
//     XOR-swizzled LDS once per step; awe exchanged block-locally via LDS.
//     128KB dynamic LDS. Wfc transpose embedded (4 tiles/block).

#define VV 50257
#define VP 50304   // 786*64
#define TT 20
#define NBLK 8     // recurrence blocks (one per 64-wide j slice of gates)

typedef __attribute__((ext_vector_type(4))) float f32x4;
typedef __attribute__((ext_vector_type(8))) short bf16x8;

#define MFMA(a,b,c) __builtin_amdgcn_mfma_f32_16x16x32_bf16((a),(b),(c),0,0,0)

__device__ __forceinline__ unsigned short f2bf(float f){
  union { float f; unsigned int u; } v; v.f = f;
  unsigned int u = v.u;
  return (unsigned short)((u + 0x7FFFu + ((u >> 16) & 1u)) >> 16);
}
__device__ __forceinline__ float sigf(float x){ return 1.f/(1.f + expf(-x)); }

__device__ __forceinline__ void gload_lds16(const unsigned short* g, unsigned short* l){
  __builtin_amdgcn_global_load_lds(
      (const __attribute__((address_space(1))) unsigned int*)g,
      (__attribute__((address_space(3))) unsigned int*)l, 16, 0, 0);
}

// ---- device-coherent (cross-XCD) bypass accessors ----
__device__ __forceinline__ void co_load16(bf16x8* d, const unsigned short* p){
  asm volatile("global_load_dwordx4 %0, %1, off sc0 sc1" : "=v"(*d) : "v"(p));
}
__device__ __forceinline__ void co_store2(unsigned short* p, unsigned short v){
  asm volatile("global_store_short %0, %1, off sc0 sc1" :: "v"(p), "v"(v) : "memory");
}
__device__ __forceinline__ unsigned int co_load_u32(const unsigned int* p){
  unsigned int r;
  asm volatile("global_load_dword %0, %1, off sc0 sc1\n\ts_waitcnt vmcnt(0)"
               : "=v"(r) : "v"(p) : "memory");
  return r;
}

// grid barrier among NBLK blocks: vmcnt drain -> relaxed agent add -> bypass spin
__device__ __forceinline__ void gbar(unsigned int* cnt, unsigned int target){
  asm volatile("s_waitcnt vmcnt(0)" ::: "memory");
  __syncthreads();
  if(threadIdx.x == 0){
    __hip_atomic_fetch_add(cnt, 1u, __ATOMIC_RELAXED, __HIP_MEMORY_SCOPE_AGENT);
    while(co_load_u32(cnt) < target) __builtin_amdgcn_s_sleep(1);
  }
  __syncthreads();
}

// ---------- prep kernels ----------

__global__ __launch_bounds__(256) void cvt_weights(const float* __restrict__ Wih,
    const float* __restrict__ Whh, unsigned short* __restrict__ Wcomb,
    unsigned short* __restrict__ We){
  int j = blockIdx.x; int tid = threadIdx.x;
  for(int q=0;q<4;q++){ int k = tid + 256*q;
    float v = (k < 512) ? Whh[j*512 + k] : Wih[j*1024 + k];
    Wcomb[(size_t)j*1024 + k] = f2bf(v); }
  for(int q=0;q<2;q++){ int k = tid + 256*q;
    We[(size_t)j*512 + k] = f2bf(Wih[j*1024 + k]); }
}

// dst[c][r] = bf16(src[r][c]); src f32 [R][C]; dst [C][R]
__global__ __launch_bounds__(256) void transpose_cvt(const float* __restrict__ src,
    unsigned short* __restrict__ dst, int R, int C){
  __shared__ float tile[64][65];
  int c0 = blockIdx.x*64, r0 = blockIdx.y*64;
  int tx = threadIdx.x & 63, ty = threadIdx.x >> 6;
  for(int i=0;i<16;i++){
    int r = ty + i*4; int sc = c0 + tx;
    tile[r][tx] = (sc < C) ? src[(size_t)(r0+r)*C + sc] : 0.f;
  }
  __syncthreads();
  for(int i=0;i<16;i++){
    int cl = ty + i*4;
    dst[(size_t)(c0+cl)*R + r0 + tx] = f2bf(tile[tx][cl]);
  }
}

__global__ __launch_bounds__(128) void build_emb(const float* __restrict__ feat,
    const float* __restrict__ emb, const int* __restrict__ cap,
    unsigned short* __restrict__ EmbMat){
  int m = blockIdx.x; int t = m >> 6, b = m & 63;
  const float* src = (t == 0) ? (feat + b*512) : (emb + (size_t)cap[b*19 + (t-1)]*512);
  for(int q=0;q<4;q++){ int k = threadIdx.x + 128*q;
    EmbMat[(size_t)m*512 + k] = f2bf(src[k]); }
}

// h0/c0 init; x0 is [64][512] h-only now
__global__ __launch_bounds__(512) void init_hc(const float* __restrict__ feat,
    const float* __restrict__ Whi, const float* __restrict__ bhi,
    const float* __restrict__ Wci, const float* __restrict__ bci,
    unsigned short* __restrict__ x0, float* __restrict__ c){
  int j = threadIdx.x; int b0 = blockIdx.x*4;
  float ah[4], ac[4];
#pragma unroll
  for(int r=0;r<4;r++){ ah[r] = bhi[j]; ac[r] = bci[j]; }
  for(int k=0;k<512;k++){
    float wh = Whi[k*512 + j], wc = Wci[k*512 + j];
#pragma unroll
    for(int r=0;r<4;r++){
      float f = feat[(b0+r)*512 + k];
      ah[r] += f*wh; ac[r] += f*wc;
    }
  }
#pragma unroll
  for(int r=0;r<4;r++){
    x0[(b0+r)*512 + j] = f2bf(ah[r]);
    c[(b0+r)*512 + j] = ac[r];
  }
}

// ---------- 128x128 NT MFMA GEMM, K=512, global_load_lds staging ----------
// EPIL 0: E4[((m*512)+col)*4 + gate] = acc + bias1[n] + bias2[n]   (n = gate*512+col)
// EPIL 1: hs rows are m = t*64+b -> out[(b*20+t)*VV+n] = mask ? acc+bias1[n] : 0
template<int EPIL>
__global__ __launch_bounds__(256) void gemm2(const unsigned short* __restrict__ Abf,
    const unsigned short* __restrict__ Bbf, const float* __restrict__ bias1,
    const float* __restrict__ bias2, const int* __restrict__ lensp,
    float* __restrict__ Cout, int MT){
  __shared__ __align__(16) unsigned short As[128*64];
  __shared__ __align__(16) unsigned short Bs[128*64];
  const int nwg = gridDim.x;
  const int id = blockIdx.x;
  const int q = nwg >> 3, rr = nwg & 7;
  const int xcd = id & 7, pos = id >> 3;
  const int work = (xcd < rr) ? (xcd*(q+1) + pos) : (rr*(q+1) + (xcd-rr)*q + pos);
  const int m0 = (work % MT) * 128;
  const int n0 = (work / MT) * 128;
  const int tid = threadIdx.x, lane = tid & 63, w = tid >> 6;
  const int wr = w >> 1, wc = w & 1;
  const int lrow = lane >> 3, lcol = (lane & 7) * 8;

  f32x4 acc[4][4];
#pragma unroll
  for(int i=0;i<4;i++)
#pragma unroll
    for(int j=0;j<4;j++) acc[i][j] = f32x4{0.f,0.f,0.f,0.f};

  for(int k0=0;k0<512;k0+=64){
    __syncthreads();
#pragma unroll
    for(int i=0;i<4;i++){
      int c = w*4 + i;
      int row = c*8 + lrow;
      gload_lds16(Abf + (size_t)(m0+row)*512 + k0 + lcol, As + c*512);
      gload_lds16(Bbf + (size_t)(n0+row)*512 + k0 + lcol, Bs + c*512);
    }
    asm volatile("s_waitcnt vmcnt(0)" ::: "memory");
    __syncthreads();
#pragma unroll
    for(int kk=0;kk<64;kk+=32){
      bf16x8 af[4], bfv[4];
#pragma unroll
      for(int mf=0;mf<4;mf++)
        af[mf] = *(const bf16x8*)(As + (wr*64 + mf*16 + (lane&15))*64 + kk + (lane>>4)*8);
#pragma unroll
      for(int nf=0;nf<4;nf++)
        bfv[nf] = *(const bf16x8*)(Bs + (wc*64 + nf*16 + (lane&15))*64 + kk + (lane>>4)*8);
#pragma unroll
      for(int mf=0;mf<4;mf++)
#pragma unroll
        for(int nf=0;nf<4;nf++)
          acc[mf][nf] = MFMA(af[mf], bfv[nf], acc[mf][nf]);
    }
  }
#pragma unroll
  for(int mf=0;mf<4;mf++)
#pragma unroll
    for(int nf=0;nf<4;nf++){
      int n = n0 + wc*64 + nf*16 + (lane & 15);
#pragma unroll
      for(int r=0;r<4;r++){
        int m = m0 + wr*64 + mf*16 + (lane>>4)*4 + r;
        float v = acc[mf][nf][r];
        if constexpr (EPIL == 0){
          int gate = n >> 9, col = n & 511;
          Cout[((size_t)m*512 + col)*4 + gate] = v + bias1[n] + bias2[n];
        } else {
          if(n < VV){
            int b = m & 63, t = m >> 6;
            float o = (t < lensp[b]) ? (v + bias1[n]) : 0.f;
            __builtin_nontemporal_store(o, &Cout[((size_t)(b*20 + t))*VV + n]);
          }
        }
      }
    }
}

// ---------- persistent recurrence: 8 blocks, ONE barrier/step ----------
// Block bk owns gates j-slice [64bk, 64bk+64) (x4 gates). Per step:
//   stage h (bypass) -> swizzled LDS hsh  -> s_barrier
//   beta: full [64][512] split across 8 waves (redundant per block) -> awe -> LDS aw
//   s_barrier -> gates (h|awe from LDS, Wcomb cached) + fused LSTM
//   -> h slice to x_next (bypass) + hs ; grid barrier (8 blocks)
// LDS: hsh 64KB + aw 64KB, both byte^=((row&7)<<4) swizzled. Blocks >=NBLK: Wfc transpose.
__global__ __launch_bounds__(512) void recur(
    const unsigned short* __restrict__ Wcomb,  // [2048][1024] bf16
    const unsigned short* __restrict__ Wbt,    // [512][512] bf16 (W_beta^T)
    const float* __restrict__ bbeta,
    const float* __restrict__ feat,            // [64][512] f32
    const float* __restrict__ E4,              // [1280][512][4] f32 gate-minor
    const float* __restrict__ c0,
    const int* __restrict__ lens,
    unsigned short* x0, unsigned short* x1,    // [64][512] bf16 h, double-buffered
    unsigned short* __restrict__ hs,           // [t*64+b][512] bf16
    unsigned int* barcnt,
    const float* __restrict__ Wfc, unsigned short* __restrict__ Wfct){
  extern __shared__ char LDS[];                // 128 KB

  if(blockIdx.x >= NBLK){
    // ---- embedded Wfc transpose: 4 tiles per block ----
    float (*tile)[65] = (float(*)[65])LDS;
    int tb = blockIdx.x - NBLK;
    int c0t = (tb % 786)*64;
    int rq = tb / 786;                          // 0..1
    int tx = threadIdx.x & 63, ty = threadIdx.x >> 6;   // ty 0..7
    for(int s=0;s<4;s++){
      int r0 = (rq*4 + s)*64;
      __syncthreads();
      for(int i=0;i<8;i++){
        int r = ty + i*8; int sc = c0t + tx;
        tile[r][tx] = (sc < VV) ? Wfc[(size_t)(r0+r)*VV + sc] : 0.f;
      }
      __syncthreads();
      for(int i=0;i<8;i++){
        int cl = ty + i*8;
        Wfct[(size_t)(c0t+cl)*512 + r0 + tx] = f2bf(tile[tx][cl]);
      }
    }
    return;
  }

  char* hsh = LDS;                 // h:   byte = row*1024 + (2k ^ ((row&7)<<4))
  char* aw  = LDS + 65536;         // awe: same swizzle
  const int tid = threadIdx.x, bk = blockIdx.x;
  const int lane = tid & 63, w = tid >> 6;     // 8 waves
  const int l15 = lane & 15, lhi = lane >> 4;
  const int kb0 = w*64;                        // beta col-slice of this wave
  const int mbase = (w & 1)*32;                // gates m-half
  const int jl0 = (w >> 1)*16;                 // gates j-quarter
  const int jcol = bk*64 + jl0 + l15;          // global j in [0,512)

  // persistent per-lane state
  float c_reg[2][4]; int ln_[2][4];
#pragma unroll
  for(int mf=0;mf<2;mf++)
#pragma unroll
    for(int r=0;r<4;r++){
      int b = mbase + mf*16 + lhi*4 + r;
      c_reg[mf][r] = c0[b*512 + jcol];
      ln_[mf][r]   = lens[b];
    }
  float bbv[4];
#pragma unroll
  for(int nf=0;nf<4;nf++) bbv[nf] = bbeta[kb0 + nf*16 + l15];

  const unsigned short* pWb[4];
#pragma unroll
  for(int nf=0;nf<4;nf++) pWb[nf] = Wbt + (size_t)(kb0 + nf*16 + l15)*512;
  const unsigned short* pG[4];
#pragma unroll
  for(int nf=0;nf<4;nf++) pG[nf] = Wcomb + (size_t)(nf*512 + jcol)*1024;

  for(int t=0;t<TT;t++){
    const unsigned short* xc = (t & 1) ? x1 : x0;
    unsigned short* xn = (t & 1) ? x0 : x1;

    // ---- stage h -> swizzled LDS (bypass reads; async-split) ----
    bf16x8 sv[8];
#pragma unroll
    for(int i=0;i<8;i++){ int chunk = tid + 512*i; co_load16(&sv[i], xc + chunk*8); }
    asm volatile("s_waitcnt vmcnt(0)" ::: "memory");
    __builtin_amdgcn_sched_barrier(0);
#pragma unroll
    for(int i=0;i<8;i++){
      int chunk = tid + 512*i;
      int row = chunk >> 6, c16 = chunk & 63;
      *(bf16x8*)(hsh + row*1024 + ((c16*16) ^ ((row & 7) << 4))) = sv[i];
    }
    __syncthreads();

    // ---- beta: M=64, N=64 (wave slice), K=512 ----
    f32x4 accb[4][4];
#pragma unroll
    for(int i=0;i<4;i++)
#pragma unroll
      for(int j=0;j<4;j++) accb[i][j] = f32x4{0.f,0.f,0.f,0.f};
#pragma unroll 4
    for(int ki=0;ki<16;ki++){
      int k = ki*32 + lhi*8;
      bf16x8 bfr[4];
#pragma unroll
      for(int nf=0;nf<4;nf++) bfr[nf] = *(const bf16x8*)(pWb[nf] + k);
#pragma unroll
      for(int mf=0;mf<4;mf++){
        int row = mf*16 + l15;
        bf16x8 afr = *(const bf16x8*)(hsh + row*1024 + ((2*k) ^ ((row & 7) << 4)));
#pragma unroll
        for(int nf=0;nf<4;nf++) accb[mf][nf] = MFMA(afr, bfr[nf], accb[mf][nf]);
      }
    }
    // awe = sigmoid(beta + b_beta) * feat -> LDS aw
#pragma unroll
    for(int mf=0;mf<4;mf++)
#pragma unroll
      for(int nf=0;nf<4;nf++){
        int kb = kb0 + nf*16 + l15;
#pragma unroll
        for(int r=0;r<4;r++){
          int b = mf*16 + lhi*4 + r;
          float g = sigf(accb[mf][nf][r] + bbv[nf]);
          float av = g * feat[b*512 + kb];
          *(unsigned short*)(aw + b*1024 + ((2*kb) ^ ((b & 7) << 4))) = f2bf(av);
        }
      }
    __syncthreads();

    // ---- gates: M=32 (wave half), N=64 (4 gates x 16 j), K=1024 ----
    f32x4 accg[2][4];
#pragma unroll
    for(int i=0;i<2;i++)
#pragma unroll
      for(int j=0;j<4;j++) accg[i][j] = f32x4{0.f,0.f,0.f,0.f};
#pragma unroll 4
    for(int ki=0;ki<32;ki++){
      int k = ki*32 + lhi*8;
      const char* abase = (k < 512) ? hsh : (aw - 1024);  // (2k^s)-1024 == (2(k-512))^s
      bf16x8 bfr[4];
#pragma unroll
      for(int nf=0;nf<4;nf++) bfr[nf] = *(const bf16x8*)(pG[nf] + k);
#pragma unroll
      for(int mf=0;mf<2;mf++){
        int row = mbase + mf*16 + l15;
        bf16x8 afr = *(const bf16x8*)(abase + row*1024 + ((2*k) ^ ((row & 7) << 4)));
#pragma unroll
        for(int nf=0;nf<4;nf++) accg[mf][nf] = MFMA(afr, bfr[nf], accg[mf][nf]);
      }
    }

    // ---- fused LSTM epilogue + h publish ----
#pragma unroll
    for(int mf=0;mf<2;mf++)
#pragma unroll
      for(int r=0;r<4;r++){
        int b = mbase + mf*16 + lhi*4 + r;
        f32x4 e4 = *(const f32x4*)(E4 + (((size_t)(t*64 + b))*512 + jcol)*4);
        float iv = sigf(accg[mf][0][r] + e4[0]);
        float fv = sigf(accg[mf][1][r] + e4[1]);
        float gv = tanhf(accg[mf][2][r] + e4[2]);
        float ov = sigf(accg[mf][3][r] + e4[3]);
        float cn = fv*c_reg[mf][r] + iv*gv;
        float hn = ov * tanhf(cn);
        bool valid = t < ln_[mf][r];
        if(valid) c_reg[mf][r] = cn;
        unsigned short hb;
        if(valid) hb = f2bf(hn);
        else hb = *(unsigned short*)(hsh + b*1024 + ((2*jcol) ^ ((b & 7) << 4)));
        hs[((size_t)(t*64 + b))*512 + jcol] = hb;
        co_store2(xn + b*512 + jcol, hb);
      }
    if(t < TT-1) gbar(barcnt, (unsigned)(t+1)*NBLK);
  }
}

// ---------- launcher ----------
extern "C" void kernel_launch(void* const* d_in, const int* in_sizes, int n_in,
                              void* d_out, int out_size, void* d_ws, size_t ws_size,
                              hipStream_t stream){
  const float* feat  = (const float*)d_in[0];
  const int*   cap   = (const int*)  d_in[1];
  const int*   lens  = (const int*)  d_in[2];
  const float* emb   = (const float*)d_in[3];
  const float* Wih   = (const float*)d_in[4];
  const float* Whh   = (const float*)d_in[5];
  const float* bih   = (const float*)d_in[6];
  const float* bhh   = (const float*)d_in[7];
  // d_in[8..13]: attention weights -- dead (enc seq len == 1)
  const float* Whi   = (const float*)d_in[14];
  const float* bhi   = (const float*)d_in[15];
  const float* Wci   = (const float*)d_in[16];
  const float* bci   = (const float*)d_in[17];
  const float* Wbeta = (const float*)d_in[18];
  const float* bbeta = (const float*)d_in[19];
  const float* Wfc   = (const float*)d_in[20];
  const float* bfc   = (const float*)d_in[21];
  float* out = (float*)d_out;

  char* ws = (char*)d_ws;
  size_t off = 0;
  auto alloc = [&](size_t bytes)->void*{
    void* p = ws + off; off += (bytes + 1023) & ~(size_t)1023; return p; };
  unsigned short* Wcomb  = (unsigned short*)alloc((size_t)2048*1024*2);
  unsigned short* We     = (unsigned short*)alloc((size_t)2048*512*2);
  unsigned short* Wbt    = (unsigned short*)alloc((size_t)512*512*2);
  unsigned short* Wfct   = (unsigned short*)alloc((size_t)VP*512*2);
  unsigned short* EmbMat = (unsigned short*)alloc((size_t)1280*512*2);
  float*          E4     = (float*)alloc((size_t)1280*2048*4);
  unsigned short* x0     = (unsigned short*)alloc((size_t)64*512*2);
  unsigned short* x1     = (unsigned short*)alloc((size_t)64*512*2);
  float*          cbuf   = (float*)alloc((size_t)64*512*4);
  unsigned short* hs     = (unsigned short*)alloc((size_t)1280*512*2);
  unsigned int*   barcnt = (unsigned int*)alloc(64);

  static_cast<void>(hipFuncSetAttribute((const void*)recur,
      hipFuncAttributeMaxDynamicSharedMemorySize, 131072));

  hipMemsetAsync(barcnt, 0, 64, stream);
  cvt_weights<<<2048, 256, 0, stream>>>(Wih, Whh, Wcomb, We);
  transpose_cvt<<<dim3(8,8), 256, 0, stream>>>(Wbeta, Wbt, 512, 512);
  build_emb<<<1280, 128, 0, stream>>>(feat, emb, cap, EmbMat);
  init_hc<<<16, 512, 0, stream>>>(feat, Whi, bhi, Wci, bci, x0, cbuf);

  // E4 = emb-part of gates + b_ih + b_hh (gate-minor): M=1280, N=2048, K=512
  gemm2<0><<<160, 256, 0, stream>>>(EmbMat, We, bih, bhh, nullptr, E4, 10);

  // persistent recurrence (blocks 0..7) + embedded Wfc transpose (1572 blocks x 4 tiles)
  recur<<<NBLK + 1572, 512, 131072, stream>>>(Wcomb, Wbt, bbeta, feat, E4, cbuf,
                                              lens, x0, x1, hs, barcnt, Wfc, Wfct);

  // preds: out[(b*20+t)][n] = mask ? hs[t*64+b] @ Wfc + b_fc : 0 ; M=1280, N=50304, K=512
  gemm2<1><<<3930, 256, 0, stream>>>(hs, Wfct, bfc, nullptr, lens, out, 10);
}

// Round 7
// 1254.659 us; speedup vs baseline: 1.3907x; 1.3907x over previous
//
#include <hip/hip_runtime.h>
#include <hip/hip_bf16.h>

// DecoderRNN: attention degenerate (enc seq len == 1 -> awe == gate*features).
// R7: recurrence = 20 per-step kernel launches (persistent/grid-barrier designs
//     measured 13-72 us/phase -- worse than launch overhead). Each step kernel:
//     32 blocks = 4 b-groups x 8 j-spans; block computes beta for its 16 b-rows
//     (redundant across j-spans, ~1us MFMA), awe -> swizzled LDS, gates with
//     nf=gate mapping, in-register LSTM. Cross-step state via plain cached
//     global memory -- kernel-boundary coherence (proven in R1).

#define VV 50257
#define VP 50304   // 786*64
#define TT 20

typedef __attribute__((ext_vector_type(4))) float f32x4;
typedef __attribute__((ext_vector_type(8))) short bf16x8;

#define MFMA(a,b,c) __builtin_amdgcn_mfma_f32_16x16x32_bf16((a),(b),(c),0,0,0)

__device__ __forceinline__ unsigned short f2bf(float f){
  union { float f; unsigned int u; } v; v.f = f;
  unsigned int u = v.u;
  return (unsigned short)((u + 0x7FFFu + ((u >> 16) & 1u)) >> 16);
}
__device__ __forceinline__ float sigf(float x){ return 1.f/(1.f + expf(-x)); }

__device__ __forceinline__ void gload_lds16(const unsigned short* g, unsigned short* l){
  __builtin_amdgcn_global_load_lds(
      (const __attribute__((address_space(1))) unsigned int*)g,
      (__attribute__((address_space(3))) unsigned int*)l, 16, 0, 0);
}

// ---------- prep kernels ----------

__global__ __launch_bounds__(256) void cvt_weights(const float* __restrict__ Wih,
    const float* __restrict__ Whh, unsigned short* __restrict__ Wcomb,
    unsigned short* __restrict__ We){
  int j = blockIdx.x; int tid = threadIdx.x;
  for(int q=0;q<4;q++){ int k = tid + 256*q;
    float v = (k < 512) ? Whh[j*512 + k] : Wih[j*1024 + k];
    Wcomb[(size_t)j*1024 + k] = f2bf(v); }
  for(int q=0;q<2;q++){ int k = tid + 256*q;
    We[(size_t)j*512 + k] = f2bf(Wih[j*1024 + k]); }
}

// dst[c][r] = bf16(src[r][c]); src f32 [R][C]; dst [C..][R]
__global__ __launch_bounds__(256) void transpose_cvt(const float* __restrict__ src,
    unsigned short* __restrict__ dst, int R, int C){
  __shared__ float tile[64][65];
  int c0 = blockIdx.x*64, r0 = blockIdx.y*64;
  int tx = threadIdx.x & 63, ty = threadIdx.x >> 6;
  for(int i=0;i<16;i++){
    int r = ty + i*4; int sc = c0 + tx;
    tile[r][tx] = (sc < C) ? src[(size_t)(r0+r)*C + sc] : 0.f;
  }
  __syncthreads();
  for(int i=0;i<16;i++){
    int cl = ty + i*4;
    dst[(size_t)(c0+cl)*R + r0 + tx] = f2bf(tile[tx][cl]);
  }
}

__global__ __launch_bounds__(128) void build_emb(const float* __restrict__ feat,
    const float* __restrict__ emb, const int* __restrict__ cap,
    unsigned short* __restrict__ EmbMat){
  int m = blockIdx.x; int t = m >> 6, b = m & 63;
  const float* src = (t == 0) ? (feat + b*512) : (emb + (size_t)cap[b*19 + (t-1)]*512);
  for(int q=0;q<4;q++){ int k = threadIdx.x + 128*q;
    EmbMat[(size_t)m*512 + k] = f2bf(src[k]); }
}

// h0/c0 init; x0 is [64][512] bf16 h
__global__ __launch_bounds__(512) void init_hc(const float* __restrict__ feat,
    const float* __restrict__ Whi, const float* __restrict__ bhi,
    const float* __restrict__ Wci, const float* __restrict__ bci,
    unsigned short* __restrict__ x0, float* __restrict__ c){
  int j = threadIdx.x; int b0 = blockIdx.x*4;
  float ah[4], ac[4];
#pragma unroll
  for(int r=0;r<4;r++){ ah[r] = bhi[j]; ac[r] = bci[j]; }
  for(int k=0;k<512;k++){
    float wh = Whi[k*512 + j], wc = Wci[k*512 + j];
#pragma unroll
    for(int r=0;r<4;r++){
      float f = feat[(b0+r)*512 + k];
      ah[r] += f*wh; ac[r] += f*wc;
    }
  }
#pragma unroll
  for(int r=0;r<4;r++){
    x0[(b0+r)*512 + j] = f2bf(ah[r]);
    c[(b0+r)*512 + j] = ac[r];
  }
}

// ---------- 128x128 NT MFMA GEMM, K=512, global_load_lds staging ----------
// EPIL 0: E4[((m*512)+col)*4 + gate] = acc + bias1[n] + bias2[n]   (n = gate*512+col)
// EPIL 1: A rows m = t*64+b -> out[(b*20+t)*VV+n] = (t<len[b]) ? acc+bias1[n] : 0
template<int EPIL>
__global__ __launch_bounds__(256) void gemm2(const unsigned short* __restrict__ Abf,
    const unsigned short* __restrict__ Bbf, const float* __restrict__ bias1,
    const float* __restrict__ bias2, const int* __restrict__ lensp,
    float* __restrict__ Cout, int MT){
  __shared__ __align__(16) unsigned short As[128*64];
  __shared__ __align__(16) unsigned short Bs[128*64];
  const int nwg = gridDim.x;
  const int id = blockIdx.x;
  const int q = nwg >> 3, rr = nwg & 7;
  const int xcd = id & 7, pos = id >> 3;
  const int work = (xcd < rr) ? (xcd*(q+1) + pos) : (rr*(q+1) + (xcd-rr)*q + pos);
  const int m0 = (work % MT) * 128;
  const int n0 = (work / MT) * 128;
  const int tid = threadIdx.x, lane = tid & 63, w = tid >> 6;
  const int wr = w >> 1, wc = w & 1;
  const int lrow = lane >> 3, lcol = (lane & 7) * 8;

  f32x4 acc[4][4];
#pragma unroll
  for(int i=0;i<4;i++)
#pragma unroll
    for(int j=0;j<4;j++) acc[i][j] = f32x4{0.f,0.f,0.f,0.f};

  for(int k0=0;k0<512;k0+=64){
    __syncthreads();
#pragma unroll
    for(int i=0;i<4;i++){
      int c = w*4 + i;
      int row = c*8 + lrow;
      gload_lds16(Abf + (size_t)(m0+row)*512 + k0 + lcol, As + c*512);
      gload_lds16(Bbf + (size_t)(n0+row)*512 + k0 + lcol, Bs + c*512);
    }
    asm volatile("s_waitcnt vmcnt(0)" ::: "memory");
    __syncthreads();
#pragma unroll
    for(int kk=0;kk<64;kk+=32){
      bf16x8 af[4], bfv[4];
#pragma unroll
      for(int mf=0;mf<4;mf++)
        af[mf] = *(const bf16x8*)(As + (wr*64 + mf*16 + (lane&15))*64 + kk + (lane>>4)*8);
#pragma unroll
      for(int nf=0;nf<4;nf++)
        bfv[nf] = *(const bf16x8*)(Bs + (wc*64 + nf*16 + (lane&15))*64 + kk + (lane>>4)*8);
#pragma unroll
      for(int mf=0;mf<4;mf++)
#pragma unroll
        for(int nf=0;nf<4;nf++)
          acc[mf][nf] = MFMA(af[mf], bfv[nf], acc[mf][nf]);
    }
  }
#pragma unroll
  for(int mf=0;mf<4;mf++)
#pragma unroll
    for(int nf=0;nf<4;nf++){
      int n = n0 + wc*64 + nf*16 + (lane & 15);
#pragma unroll
      for(int r=0;r<4;r++){
        int m = m0 + wr*64 + mf*16 + (lane>>4)*4 + r;
        float v = acc[mf][nf][r];
        if constexpr (EPIL == 0){
          int gate = n >> 9, col = n & 511;
          Cout[((size_t)m*512 + col)*4 + gate] = v + bias1[n] + bias2[n];
        } else {
          if(n < VV){
            int b = m & 63, t = m >> 6;
            float o = (t < lensp[b]) ? (v + bias1[n]) : 0.f;
            __builtin_nontemporal_store(o, &Cout[((size_t)(b*20 + t))*VV + n]);
          }
        }
      }
    }
}

// ---------- per-step fused kernel: beta(16 own b-rows) + awe + gates + LSTM ----------
// grid 32 = 4 b-groups x 8 j-spans; 256 thr (4 waves). Wave w:
//   phase A: beta j-slice [w*128,(w+1)*128) for b-rows [B0,B0+16) -> awe -> LDS
//   phase B: gates j-sub [j0+w*16, +16), nf = gate; K=1024 (h global | awe LDS)
// LDS aw[16][512] bf16, byte ^= ((row&7)<<4) swizzle.
__global__ __launch_bounds__(256) void step_k(
    const unsigned short* __restrict__ Wcomb,  // [2048][1024] bf16
    const unsigned short* __restrict__ Wbt,    // [512][512] bf16 (W_beta^T)
    const float* __restrict__ bbeta,
    const float* __restrict__ feat,            // [64][512] f32
    const float* __restrict__ E4,              // [1280][512][4] f32 gate-minor
    float* __restrict__ c,                     // [64][512] f32 (persistent)
    const int* __restrict__ lens,
    const unsigned short* __restrict__ xc,     // [64][512] bf16 h (in)
    unsigned short* __restrict__ xn,           // [64][512] bf16 h (out)
    unsigned short* __restrict__ hs,           // [t*64+b][512] bf16
    int t){
  __shared__ __align__(16) char aw[16*1024];
  const int tid = threadIdx.x;
  const int lane = tid & 63, w = tid >> 6;
  const int l15 = lane & 15, lhi = lane >> 4;
  const int bg = blockIdx.x >> 3, js = blockIdx.x & 7;
  const int B0 = bg*16, j0 = js*64;
  const unsigned short* pA = xc + (size_t)(B0 + l15)*512 + lhi*8;

  // ---- phase A: beta
  f32x4 accb[8];
#pragma unroll
  for(int i=0;i<8;i++) accb[i] = f32x4{0.f,0.f,0.f,0.f};
#pragma unroll 4
  for(int ks=0; ks<16; ks++){
    int k = ks*32;
    bf16x8 a = *(const bf16x8*)(pA + k);
#pragma unroll
    for(int nf=0; nf<8; nf++){
      bf16x8 b = *(const bf16x8*)(Wbt + (size_t)(w*128 + nf*16 + l15)*512 + k + lhi*8);
      accb[nf] = MFMA(a, b, accb[nf]);
    }
  }
#pragma unroll
  for(int nf=0; nf<8; nf++){
    int jb = w*128 + nf*16 + l15;
    float bb = bbeta[jb];
#pragma unroll
    for(int r=0;r<4;r++){
      int row = lhi*4 + r;
      float g = sigf(accb[nf][r] + bb);
      float av = g * feat[(size_t)(B0+row)*512 + jb];
      *(unsigned short*)(aw + row*1024 + ((2*jb) ^ ((row & 7) << 4))) = f2bf(av);
    }
  }
  __syncthreads();

  // ---- phase B: gates
  const int j = j0 + w*16 + l15;
  f32x4 accg[4];
#pragma unroll
  for(int i=0;i<4;i++) accg[i] = f32x4{0.f,0.f,0.f,0.f};
  const unsigned short* pG0 = Wcomb + (size_t)(0*512 + j)*1024 + lhi*8;
  const unsigned short* pG1 = Wcomb + (size_t)(1*512 + j)*1024 + lhi*8;
  const unsigned short* pG2 = Wcomb + (size_t)(2*512 + j)*1024 + lhi*8;
  const unsigned short* pG3 = Wcomb + (size_t)(3*512 + j)*1024 + lhi*8;
#pragma unroll 4
  for(int ks=0; ks<16; ks++){          // k 0..511: h from global (L1/L2-hot)
    int k = ks*32;
    bf16x8 a = *(const bf16x8*)(pA + k);
    accg[0] = MFMA(a, *(const bf16x8*)(pG0 + k), accg[0]);
    accg[1] = MFMA(a, *(const bf16x8*)(pG1 + k), accg[1]);
    accg[2] = MFMA(a, *(const bf16x8*)(pG2 + k), accg[2]);
    accg[3] = MFMA(a, *(const bf16x8*)(pG3 + k), accg[3]);
  }
#pragma unroll 4
  for(int ks=0; ks<16; ks++){          // k 512..1023: awe from LDS
    int kloc = ks*32 + lhi*8;
    bf16x8 a = *(const bf16x8*)(aw + l15*1024 + ((2*kloc) ^ ((l15 & 7) << 4)));
    int k = 512 + ks*32;
    accg[0] = MFMA(a, *(const bf16x8*)(pG0 + k), accg[0]);
    accg[1] = MFMA(a, *(const bf16x8*)(pG1 + k), accg[1]);
    accg[2] = MFMA(a, *(const bf16x8*)(pG2 + k), accg[2]);
    accg[3] = MFMA(a, *(const bf16x8*)(pG3 + k), accg[3]);
  }

  // ---- fused LSTM epilogue
#pragma unroll
  for(int r=0;r<4;r++){
    int b = B0 + lhi*4 + r;
    f32x4 e4 = *(const f32x4*)(E4 + (((size_t)(t*64 + b))*512 + j)*4);
    float iv = sigf(accg[0][r] + e4[0]);
    float fv = sigf(accg[1][r] + e4[1]);
    float gv = tanhf(accg[2][r] + e4[2]);
    float ov = sigf(accg[3][r] + e4[3]);
    float cold = c[(size_t)b*512 + j];
    float cn = fv*cold + iv*gv;
    float hn = ov * tanhf(cn);
    bool valid = t < lens[b];
    if(valid) c[(size_t)b*512 + j] = cn;
    unsigned short hb = valid ? f2bf(hn) : xc[(size_t)b*512 + j];
    hs[((size_t)(t*64 + b))*512 + j] = hb;
    xn[(size_t)b*512 + j] = hb;
  }
}

// ---------- launcher ----------
extern "C" void kernel_launch(void* const* d_in, const int* in_sizes, int n_in,
                              void* d_out, int out_size, void* d_ws, size_t ws_size,
                              hipStream_t stream){
  const float* feat  = (const float*)d_in[0];
  const int*   cap   = (const int*)  d_in[1];
  const int*   lens  = (const int*)  d_in[2];
  const float* emb   = (const float*)d_in[3];
  const float* Wih   = (const float*)d_in[4];
  const float* Whh   = (const float*)d_in[5];
  const float* bih   = (const float*)d_in[6];
  const float* bhh   = (const float*)d_in[7];
  // d_in[8..13]: attention weights -- dead (enc seq len == 1)
  const float* Whi   = (const float*)d_in[14];
  const float* bhi   = (const float*)d_in[15];
  const float* Wci   = (const float*)d_in[16];
  const float* bci   = (const float*)d_in[17];
  const float* Wbeta = (const float*)d_in[18];
  const float* bbeta = (const float*)d_in[19];
  const float* Wfc   = (const float*)d_in[20];
  const float* bfc   = (const float*)d_in[21];
  float* out = (float*)d_out;

  char* ws = (char*)d_ws;
  size_t off = 0;
  auto alloc = [&](size_t bytes)->void*{
    void* p = ws + off; off += (bytes + 1023) & ~(size_t)1023; return p; };
  unsigned short* Wcomb  = (unsigned short*)alloc((size_t)2048*1024*2);
  unsigned short* We     = (unsigned short*)alloc((size_t)2048*512*2);
  unsigned short* Wbt    = (unsigned short*)alloc((size_t)512*512*2);
  unsigned short* Wfct   = (unsigned short*)alloc((size_t)VP*512*2);
  unsigned short* EmbMat = (unsigned short*)alloc((size_t)1280*512*2);
  float*          E4     = (float*)alloc((size_t)1280*2048*4);
  unsigned short* x0     = (unsigned short*)alloc((size_t)64*512*2);
  unsigned short* x1     = (unsigned short*)alloc((size_t)64*512*2);
  float*          cbuf   = (float*)alloc((size_t)64*512*4);
  unsigned short* hs     = (unsigned short*)alloc((size_t)1280*512*2);

  cvt_weights<<<2048, 256, 0, stream>>>(Wih, Whh, Wcomb, We);
  transpose_cvt<<<dim3(8,8),   256, 0, stream>>>(Wbeta, Wbt, 512, 512);
  transpose_cvt<<<dim3(786,8), 256, 0, stream>>>(Wfc,  Wfct, 512, VV);
  build_emb<<<1280, 128, 0, stream>>>(feat, emb, cap, EmbMat);
  init_hc<<<16, 512, 0, stream>>>(feat, Whi, bhi, Wci, bci, x0, cbuf);

  // E4 = emb-part of gates + b_ih + b_hh (gate-minor): M=1280, N=2048, K=512
  gemm2<0><<<160, 256, 0, stream>>>(EmbMat, We, bih, bhh, nullptr, E4, 10);

  // 20 per-step kernels; cross-step coherence via kernel boundaries
  for(int t=0;t<TT;t++){
    const unsigned short* xc = (t & 1) ? x1 : x0;
    unsigned short* xn = (t & 1) ? x0 : x1;
    step_k<<<32, 256, 0, stream>>>(Wcomb, Wbt, bbeta, feat, E4, cbuf, lens,
                                   xc, xn, hs, t);
  }

  // preds: out[(b*20+t)][n] = mask ? hs[t*64+b] @ Wfc + b_fc : 0
  gemm2<1><<<3930, 256, 0, stream>>>(hs, Wfct, bfc, nullptr, lens, out, 10);
}

// Round 8
// 613.578 us; speedup vs baseline: 2.8437x; 2.0448x over previous
//
#include <hip/hip_runtime.h>
#include <hip/hip_bf16.h>

// DecoderRNN: attention degenerate (enc seq len == 1 -> awe == gate*features).
// R8: (1) recurrence pinned to ONE XCD: 32 worker blocks identified via
//     s_getreg(HW_REG_XCC_ID)==0 + ticket; 160KB LDS (Wcomb slice 128K + Wbt 16K
//     + stage 16K) forces 1 block/CU -> the 32 claimants are co-resident on
//     XCD0's 32 CUs. h/awe exchanged through XCD0's L2 via sc0 (L1-bypass);
//     barriers are L2-local atomics (no cross-XCD flushes). Weights LDS-resident
//     for all 20 steps. Other blocks run the Wfc transpose via ticket.
//     (2) final GEMM epilogue: LDS transpose -> lane-shifted 16B-aligned
//     dwordx4 stores (512B runs) to kill write-allocate RMW fetches (R1/R7 diag).

#define VV 50257
#define VP 50304   // 786*64
#define TT 20
#define NWRK 32
#define NTILES 6288  // 786 * 8 transpose tiles

typedef __attribute__((ext_vector_type(4))) float f32x4;
typedef __attribute__((ext_vector_type(8))) short bf16x8;

#define MFMA(a,b,c) __builtin_amdgcn_mfma_f32_16x16x32_bf16((a),(b),(c),0,0,0)

__device__ __forceinline__ unsigned short f2bf(float f){
  union { float f; unsigned int u; } v; v.f = f;
  unsigned int u = v.u;
  return (unsigned short)((u + 0x7FFFu + ((u >> 16) & 1u)) >> 16);
}
__device__ __forceinline__ float sigf(float x){ return 1.f/(1.f + expf(-x)); }

__device__ __forceinline__ void gload_lds16(const unsigned short* g, unsigned short* l){
  __builtin_amdgcn_global_load_lds(
      (const __attribute__((address_space(1))) unsigned int*)g,
      (__attribute__((address_space(3))) unsigned int*)l, 16, 0, 0);
}

// ---- L1-bypass (L2-coherent within an XCD) accessors ----
__device__ __forceinline__ void co_load16(bf16x8* d, const unsigned short* p){
  asm volatile("global_load_dwordx4 %0, %1, off sc0 sc1" : "=v"(*d) : "v"(p));
}
__device__ __forceinline__ void co_store2(unsigned short* p, unsigned short v){
  asm volatile("global_store_short %0, %1, off sc0 sc1" :: "v"(p), "v"(v) : "memory");
}
__device__ __forceinline__ unsigned int co_load_u32(const unsigned int* p){
  unsigned int r;
  asm volatile("global_load_dword %0, %1, off sc0 sc1\n\ts_waitcnt vmcnt(0)"
               : "=v"(r) : "v"(p) : "memory");
  return r;
}

// barrier among the 32 same-XCD workers: all traffic stays in XCD0's L2
__device__ __forceinline__ void gbar(unsigned int* cnt, unsigned int target){
  asm volatile("s_waitcnt vmcnt(0)" ::: "memory");
  __syncthreads();
  if(threadIdx.x == 0){
    atomicAdd(cnt, 1u);
    while(co_load_u32(cnt) < target) __builtin_amdgcn_s_sleep(1);
  }
  __syncthreads();
}

// ---------- prep kernels ----------

__global__ __launch_bounds__(256) void cvt_weights(const float* __restrict__ Wih,
    const float* __restrict__ Whh, unsigned short* __restrict__ Wcomb,
    unsigned short* __restrict__ We){
  int j = blockIdx.x; int tid = threadIdx.x;
  for(int q=0;q<4;q++){ int k = tid + 256*q;
    float v = (k < 512) ? Whh[j*512 + k] : Wih[j*1024 + k];
    Wcomb[(size_t)j*1024 + k] = f2bf(v); }
  for(int q=0;q<2;q++){ int k = tid + 256*q;
    We[(size_t)j*512 + k] = f2bf(Wih[j*1024 + k]); }
}

__global__ __launch_bounds__(256) void transpose_cvt(const float* __restrict__ src,
    unsigned short* __restrict__ dst, int R, int C){
  __shared__ float tile[64][65];
  int c0 = blockIdx.x*64, r0 = blockIdx.y*64;
  int tx = threadIdx.x & 63, ty = threadIdx.x >> 6;
  for(int i=0;i<16;i++){
    int r = ty + i*4; int sc = c0 + tx;
    tile[r][tx] = (sc < C) ? src[(size_t)(r0+r)*C + sc] : 0.f;
  }
  __syncthreads();
  for(int i=0;i<16;i++){
    int cl = ty + i*4;
    dst[(size_t)(c0+cl)*R + r0 + tx] = f2bf(tile[tx][cl]);
  }
}

__global__ __launch_bounds__(128) void build_emb(const float* __restrict__ feat,
    const float* __restrict__ emb, const int* __restrict__ cap,
    unsigned short* __restrict__ EmbMat){
  int m = blockIdx.x; int t = m >> 6, b = m & 63;
  const float* src = (t == 0) ? (feat + b*512) : (emb + (size_t)cap[b*19 + (t-1)]*512);
  for(int q=0;q<4;q++){ int k = threadIdx.x + 128*q;
    EmbMat[(size_t)m*512 + k] = f2bf(src[k]); }
}

__global__ __launch_bounds__(512) void init_hc(const float* __restrict__ feat,
    const float* __restrict__ Whi, const float* __restrict__ bhi,
    const float* __restrict__ Wci, const float* __restrict__ bci,
    unsigned short* __restrict__ x0, float* __restrict__ c){
  int j = threadIdx.x; int b0 = blockIdx.x*4;
  float ah[4], ac[4];
#pragma unroll
  for(int r=0;r<4;r++){ ah[r] = bhi[j]; ac[r] = bci[j]; }
  for(int k=0;k<512;k++){
    float wh = Whi[k*512 + j], wc = Wci[k*512 + j];
#pragma unroll
    for(int r=0;r<4;r++){
      float f = feat[(b0+r)*512 + k];
      ah[r] += f*wh; ac[r] += f*wc;
    }
  }
#pragma unroll
  for(int r=0;r<4;r++){
    x0[(b0+r)*512 + j] = f2bf(ah[r]);
    c[(b0+r)*512 + j] = ac[r];
  }
}

// ---------- 128x128 NT MFMA GEMM, K=512, global_load_lds staging ----------
// EPIL 0: E4[((m*512)+col)*4 + gate] = acc + bias1[n] + bias2[n]
// EPIL 1: out rows m = b*20+t; LDS-transpose epilogue with aligned 512B runs
template<int EPIL>
__global__ __launch_bounds__(256) void gemm2(const unsigned short* __restrict__ Abf,
    const unsigned short* __restrict__ Bbf, const float* __restrict__ bias1,
    const float* __restrict__ bias2, const int* __restrict__ lensp,
    float* __restrict__ Cout, int MT){
  __shared__ __align__(16) char smem[32768];
  unsigned short* As = (unsigned short*)smem;
  unsigned short* Bs = (unsigned short*)(smem + 16384);
  float* et = (float*)smem;

  const int nwg = gridDim.x;
  const int id = blockIdx.x;
  const int q = nwg >> 3, rr = nwg & 7;
  const int xcd = id & 7, pos = id >> 3;
  const int work = (xcd < rr) ? (xcd*(q+1) + pos) : (rr*(q+1) + (xcd-rr)*q + pos);
  const int m0 = (work % MT) * 128;
  const int n0 = (work / MT) * 128;
  const int tid = threadIdx.x, lane = tid & 63, w = tid >> 6;
  const int wr = w >> 1, wc = w & 1;
  const int lrow = lane >> 3, lcol = (lane & 7) * 8;
  const int l15 = lane & 15, lhi = lane >> 4;

  f32x4 acc[4][4];
#pragma unroll
  for(int i=0;i<4;i++)
#pragma unroll
    for(int j=0;j<4;j++) acc[i][j] = f32x4{0.f,0.f,0.f,0.f};

  for(int k0=0;k0<512;k0+=64){
    __syncthreads();
#pragma unroll
    for(int i=0;i<4;i++){
      int c = w*4 + i;
      int row = c*8 + lrow;
      gload_lds16(Abf + (size_t)(m0+row)*512 + k0 + lcol, As + c*512);
      gload_lds16(Bbf + (size_t)(n0+row)*512 + k0 + lcol, Bs + c*512);
    }
    asm volatile("s_waitcnt vmcnt(0)" ::: "memory");
    __syncthreads();
#pragma unroll
    for(int kk=0;kk<64;kk+=32){
      bf16x8 af[4], bfv[4];
#pragma unroll
      for(int mf=0;mf<4;mf++)
        af[mf] = *(const bf16x8*)(As + (wr*64 + mf*16 + l15)*64 + kk + lhi*8);
#pragma unroll
      for(int nf=0;nf<4;nf++)
        bfv[nf] = *(const bf16x8*)(Bs + (wc*64 + nf*16 + l15)*64 + kk + lhi*8);
#pragma unroll
      for(int mf=0;mf<4;mf++)
#pragma unroll
        for(int nf=0;nf<4;nf++)
          acc[mf][nf] = MFMA(af[mf], bfv[nf], acc[mf][nf]);
    }
  }

  if constexpr (EPIL == 0){
#pragma unroll
    for(int mf=0;mf<4;mf++)
#pragma unroll
      for(int nf=0;nf<4;nf++){
        int n = n0 + wc*64 + nf*16 + l15;
#pragma unroll
        for(int r=0;r<4;r++){
          int m = m0 + wr*64 + mf*16 + lhi*4 + r;
          int gate = n >> 9, col = n & 511;
          Cout[((size_t)m*512 + col)*4 + gate] = acc[mf][nf][r] + bias1[n] + bias2[n];
        }
      }
  } else {
    const bool edge = (n0 + 128 > VV);
    for(int half=0; half<2; half++){
      __syncthreads();
      if(wr == half){
#pragma unroll
        for(int mf=0;mf<4;mf++)
#pragma unroll
          for(int nf=0;nf<4;nf++){
            int n = n0 + wc*64 + nf*16 + l15;
#pragma unroll
            for(int r=0;r<4;r++){
              int m = m0 + half*64 + mf*16 + lhi*4 + r;
              int b = m/20, tt = m%20;
              float v = (tt < lensp[b]) ? (acc[mf][nf][r] + bias1[n]) : 0.f;
              et[(mf*16 + lhi*4 + r)*128 + wc*64 + nf*16 + l15] = v;
            }
          }
      }
      __syncthreads();
#pragma unroll
      for(int qq=0;qq<8;qq++){
        int idx = tid + 256*qq;
        int row = idx >> 5, c4 = idx & 31;
        int m = m0 + half*64 + row;
        const float* er = et + row*128;
        if(!edge){
          size_t bdw = (size_t)m*VV + n0;
          int al = (int)((4 - (bdw & 3)) & 3);
          int chunks = (128 - al) >> 2;
          int tail = (128 - al) & 3;
          if(c4 < chunks){
            int s0 = al + c4*4;
            f32x4 v; v[0]=er[s0]; v[1]=er[s0+1]; v[2]=er[s0+2]; v[3]=er[s0+3];
            *(f32x4*)(Cout + bdw + s0) = v;           // 16B-aligned by construction
          }
          if(c4 < al) Cout[bdw + c4] = er[c4];
          if(c4 < tail){ int s1 = al + chunks*4 + c4; Cout[bdw + s1] = er[s1]; }
        } else {
#pragma unroll
          for(int i=0;i<4;i++){
            int cg = n0 + c4*4 + i;
            if(cg < VV) Cout[(size_t)m*VV + cg] = er[c4*4 + i];
          }
        }
      }
    }
  }
}

// ---------- single-XCD persistent recurrence + ticketed Wfc transpose ----------
// Workers (32, all on XCD0): block owns jj-slice [16w,16w+16) of the hidden dim.
// Per step: 4 h-chunks {stage 16KB from x via sc0 -> beta+gates MFMA from LDS} ->
// awe -> aw(sc0) -> L2 barrier -> 4 awe-chunks -> LSTM -> h -> x(sc0), hs -> barrier.
// LDS: Wcomb slice [64][1024] swz @0 (128K), Wbt [16][512] swz @128K, stage @144K.
__global__ __launch_bounds__(256) void recur(
    const unsigned short* __restrict__ Wcomb,  // [2048][1024] bf16
    const unsigned short* __restrict__ Wbt,    // [512][512] bf16 (W_beta^T)
    const float* __restrict__ bbeta,
    const float* __restrict__ feat,            // [64][512] f32
    const float* __restrict__ E4,              // [(t*64+b)*512+j][4] f32 gate-minor
    const float* __restrict__ c0,
    const int* __restrict__ lens,
    unsigned short* xbuf,                      // [64][512] bf16 h (single buffer)
    unsigned short* awbuf,                     // [64][512] bf16 awe
    unsigned short* __restrict__ hs,           // [(b*20+t)][512] bf16
    unsigned int* ctrs,                        // [0]=worker tk, [16]=tp tk, [32]=bar
    const float* __restrict__ Wfc, unsigned short* __restrict__ Wfct){
  extern __shared__ char LDS[];
  char* WCb = LDS;            // 131072
  char* WBb = LDS + 131072;   // 16384
  char* STb = LDS + 147456;   // 16384
  int* lsh = (int*)LDS;
  const int tid = threadIdx.x;

  // ---- role assignment ----
  if(tid == 0){
    unsigned xcc = 99;
    asm volatile("s_getreg_b32 %0, hwreg(HW_REG_XCC_ID)" : "=s"(xcc));
    unsigned my = 0xffffffffu;
    if(xcc == 0) my = atomicAdd(&ctrs[0], 1u);
    lsh[0] = (my < NWRK) ? 1 : 0;
    lsh[1] = (int)my;
  }
  __syncthreads();
  const int iswork = lsh[0];
  const int widx = lsh[1];
  __syncthreads();

  if(!iswork){
    // ---- Wfc transpose via ticket ----
    float (*tile)[65] = (float(*)[65])LDS;
    int tx = tid & 63, ty = tid >> 6;
    for(;;){
      __syncthreads();
      if(tid == 0) lsh[0] = (int)atomicAdd(&ctrs[16], 1u);
      __syncthreads();
      int tb = lsh[0];
      __syncthreads();
      if(tb >= NTILES) return;
      int c0t = (tb % 786)*64, r0 = (tb / 786)*64;
      for(int i=0;i<16;i++){
        int r = ty + i*4; int sc = c0t + tx;
        tile[r][tx] = (sc < VV) ? Wfc[(size_t)(r0+r)*VV + sc] : 0.f;
      }
      __syncthreads();
      for(int i=0;i<16;i++){
        int cl = ty + i*4;
        Wfct[(size_t)(c0t+cl)*512 + r0 + tx] = f2bf(tile[tx][cl]);
      }
    }
  }

  // ---- worker ----
  const int lane = tid & 63, w = tid >> 6;
  const int l15 = lane & 15, lhi = lane >> 4;
  const int jj0 = widx * 16;
  const int jj = jj0 + l15;
  const int arow = w*16 + l15;
  unsigned int* barcnt = &ctrs[32];

  // stage Wcomb slice [64 gr][1024], gr = gate*16 + rl <- global row gate*512+jj0+rl
  for(int cid = tid; cid < 8192; cid += 256){
    int gr = cid >> 7, cc = cid & 127;
    size_t g = (size_t)(gr >> 4)*512 + jj0 + (gr & 15);
    bf16x8 v = *(const bf16x8*)(Wcomb + g*1024 + cc*8);
    *(bf16x8*)(WCb + gr*2048 + ((cc*16) ^ ((gr & 7) << 4))) = v;
  }
  // stage Wbt slice [16][512] <- rows jj0..jj0+15
  for(int cid = tid; cid < 1024; cid += 256){
    int r = cid >> 6, cc = cid & 63;
    bf16x8 v = *(const bf16x8*)(Wbt + (size_t)(jj0 + r)*512 + cc*8);
    *(bf16x8*)(WBb + r*1024 + ((cc*16) ^ ((r & 7) << 4))) = v;
  }

  float c_reg[4], fe[4]; int ln[4];
#pragma unroll
  for(int r=0;r<4;r++){
    int b = w*16 + lhi*4 + r;
    c_reg[r] = c0[b*512 + jj];
    fe[r]    = feat[b*512 + jj];
    ln[r]    = lens[b];
  }
  const float bb = bbeta[jj];
  const int kc_h = widx >> 3;      // h-chunk containing this block's jj columns
  __syncthreads();

  for(int t=0;t<TT;t++){
    f32x4 acca = f32x4{0.f,0.f,0.f,0.f};
    f32x4 accg[4];
#pragma unroll
    for(int i=0;i<4;i++) accg[i] = f32x4{0.f,0.f,0.f,0.f};
    unsigned short hold[4];

    // ---- h chunks: beta + gates(h half) ----
    for(int kc=0; kc<4; kc++){
      __syncthreads();
      bf16x8 sv[4];
#pragma unroll
      for(int qq=0;qq<4;qq++){
        int cid = tid + 256*qq; int row = cid >> 4, cc = cid & 15;
        co_load16(&sv[qq], xbuf + row*512 + kc*128 + cc*8);
      }
      asm volatile("s_waitcnt vmcnt(0)" ::: "memory");
      __builtin_amdgcn_sched_barrier(0);
#pragma unroll
      for(int qq=0;qq<4;qq++){
        int cid = tid + 256*qq; int row = cid >> 4, cc = cid & 15;
        *(bf16x8*)(STb + row*256 + ((cc*16) ^ ((row & 7) << 4))) = sv[qq];
      }
      __syncthreads();
      if(kc == kc_h){                       // capture old h for hold-masking
#pragma unroll
        for(int r=0;r<4;r++){
          int b = w*16 + lhi*4 + r;
          int cl2 = 2*(jj & 127);
          hold[r] = *(const unsigned short*)(STb + b*256 + (cl2 ^ ((b & 7) << 4)));
        }
      }
#pragma unroll
      for(int ks=0; ks<4; ks++){
        int kl2 = ks*64 + lhi*16;
        int kg2 = kc*256 + kl2;
        bf16x8 a = *(const bf16x8*)(STb + arow*256 + (kl2 ^ ((arow & 7) << 4)));
        bf16x8 wb = *(const bf16x8*)(WBb + l15*1024 + (kg2 ^ ((l15 & 7) << 4)));
        acca = MFMA(a, wb, acca);
#pragma unroll
        for(int nf=0; nf<4; nf++){
          int gr = nf*16 + l15;
          bf16x8 wg = *(const bf16x8*)(WCb + gr*2048 + (kg2 ^ ((gr & 7) << 4)));
          accg[nf] = MFMA(a, wg, accg[nf]);
        }
      }
    }
    // awe = sigmoid(beta + b_beta) * feat -> aw (sc0)
#pragma unroll
    for(int r=0;r<4;r++){
      int b = w*16 + lhi*4 + r;
      float g = sigf(acca[r] + bb);
      co_store2(awbuf + b*512 + jj, f2bf(g * fe[r]));
    }
    gbar(barcnt, (unsigned)(2*t+1)*NWRK);

    // prefetch E4 for this (t, b-rows, jj)
    f32x4 e4v[4];
#pragma unroll
    for(int r=0;r<4;r++){
      int b = w*16 + lhi*4 + r;
      e4v[r] = *(const f32x4*)(E4 + (((size_t)(t*64 + b))*512 + jj)*4);
    }

    // ---- awe chunks: gates(awe half) ----
    for(int kc=0; kc<4; kc++){
      __syncthreads();
      bf16x8 sv[4];
#pragma unroll
      for(int qq=0;qq<4;qq++){
        int cid = tid + 256*qq; int row = cid >> 4, cc = cid & 15;
        co_load16(&sv[qq], awbuf + row*512 + kc*128 + cc*8);
      }
      asm volatile("s_waitcnt vmcnt(0)" ::: "memory");
      __builtin_amdgcn_sched_barrier(0);
#pragma unroll
      for(int qq=0;qq<4;qq++){
        int cid = tid + 256*qq; int row = cid >> 4, cc = cid & 15;
        *(bf16x8*)(STb + row*256 + ((cc*16) ^ ((row & 7) << 4))) = sv[qq];
      }
      __syncthreads();
#pragma unroll
      for(int ks=0; ks<4; ks++){
        int kl2 = ks*64 + lhi*16;
        int kg2 = 1024 + kc*256 + kl2;
        bf16x8 a = *(const bf16x8*)(STb + arow*256 + (kl2 ^ ((arow & 7) << 4)));
#pragma unroll
        for(int nf=0; nf<4; nf++){
          int gr = nf*16 + l15;
          bf16x8 wg = *(const bf16x8*)(WCb + gr*2048 + (kg2 ^ ((gr & 7) << 4)));
          accg[nf] = MFMA(a, wg, accg[nf]);
        }
      }
    }

    // ---- fused LSTM epilogue ----
#pragma unroll
    for(int r=0;r<4;r++){
      int b = w*16 + lhi*4 + r;
      float iv = sigf(accg[0][r] + e4v[r][0]);
      float fv = sigf(accg[1][r] + e4v[r][1]);
      float gv = tanhf(accg[2][r] + e4v[r][2]);
      float ov = sigf(accg[3][r] + e4v[r][3]);
      float cn = fv*c_reg[r] + iv*gv;
      float hn = ov * tanhf(cn);
      bool valid = t < ln[r];
      if(valid) c_reg[r] = cn;
      unsigned short hb = valid ? f2bf(hn) : hold[r];
      hs[((size_t)(b*20 + t))*512 + jj] = hb;
      co_store2(xbuf + b*512 + jj, hb);
    }
    if(t < TT-1) gbar(barcnt, (unsigned)(2*t+2)*NWRK);
  }
}

// ---------- launcher ----------
extern "C" void kernel_launch(void* const* d_in, const int* in_sizes, int n_in,
                              void* d_out, int out_size, void* d_ws, size_t ws_size,
                              hipStream_t stream){
  const float* feat  = (const float*)d_in[0];
  const int*   cap   = (const int*)  d_in[1];
  const int*   lens  = (const int*)  d_in[2];
  const float* emb   = (const float*)d_in[3];
  const float* Wih   = (const float*)d_in[4];
  const float* Whh   = (const float*)d_in[5];
  const float* bih   = (const float*)d_in[6];
  const float* bhh   = (const float*)d_in[7];
  // d_in[8..13]: attention weights -- dead (enc seq len == 1)
  const float* Whi   = (const float*)d_in[14];
  const float* bhi   = (const float*)d_in[15];
  const float* Wci   = (const float*)d_in[16];
  const float* bci   = (const float*)d_in[17];
  const float* Wbeta = (const float*)d_in[18];
  const float* bbeta = (const float*)d_in[19];
  const float* Wfc   = (const float*)d_in[20];
  const float* bfc   = (const float*)d_in[21];
  float* out = (float*)d_out;

  char* ws = (char*)d_ws;
  size_t off = 0;
  auto alloc = [&](size_t bytes)->void*{
    void* p = ws + off; off += (bytes + 1023) & ~(size_t)1023; return p; };
  unsigned short* Wcomb  = (unsigned short*)alloc((size_t)2048*1024*2);
  unsigned short* We     = (unsigned short*)alloc((size_t)2048*512*2);
  unsigned short* Wbt    = (unsigned short*)alloc((size_t)512*512*2);
  unsigned short* Wfct   = (unsigned short*)alloc((size_t)VP*512*2);
  unsigned short* EmbMat = (unsigned short*)alloc((size_t)1280*512*2);
  float*          E4     = (float*)alloc((size_t)1280*2048*4);
  unsigned short* xbuf   = (unsigned short*)alloc((size_t)64*512*2);
  unsigned short* awbuf  = (unsigned short*)alloc((size_t)64*512*2);
  float*          cbuf   = (float*)alloc((size_t)64*512*4);
  unsigned short* hs     = (unsigned short*)alloc((size_t)1280*512*2);
  unsigned int*   ctrs   = (unsigned int*)alloc(256);

  static_cast<void>(hipFuncSetAttribute((const void*)recur,
      hipFuncAttributeMaxDynamicSharedMemorySize, 163840));

  hipMemsetAsync(ctrs, 0, 256, stream);
  cvt_weights<<<2048, 256, 0, stream>>>(Wih, Whh, Wcomb, We);
  transpose_cvt<<<dim3(8,8), 256, 0, stream>>>(Wbeta, Wbt, 512, 512);
  build_emb<<<1280, 128, 0, stream>>>(feat, emb, cap, EmbMat);
  init_hc<<<16, 512, 0, stream>>>(feat, Whi, bhi, Wci, bci, xbuf, cbuf);

  // E4 = emb-part of gates + b_ih + b_hh (gate-minor): M=1280, N=2048, K=512
  gemm2<0><<<160, 256, 0, stream>>>(EmbMat, We, bih, bhh, nullptr, E4, 10);

  // single-XCD recurrence + ticketed Wfc transpose
  recur<<<2080, 256, 163840, stream>>>(Wcomb, Wbt, bbeta, feat, E4, cbuf, lens,
                                       xbuf, awbuf, hs, ctrs, Wfc, Wfct);

  // preds: out[m = b*20+t][n] = mask ? hs @ Wfc + b_fc : 0 ; M=1280, N=50304, K=512
  gemm2<1><<<3930, 256, 0, stream>>>(hs, Wfct, bfc, nullptr, lens, out, 10);
}

// Round 9
// 598.345 us; speedup vs baseline: 2.9161x; 1.0255x over previous
//
#include <hip/hip_runtime.h>
#include <hip/hip_bf16.h>

// DecoderRNN: attention degenerate (enc seq len == 1 -> awe == gate*features).
// R9: single-XCD persistent recurrence, reworked fabric:
//   - h/awe exchange sc0-ONLY (XCD0 L2-local; producer+consumer share one L2)
//   - no LDS staging: per-phase 16 A-fragments batch-loaded to registers
//   - flag barrier: flags[w]=phase (sc0 sc1 after vmcnt drain), spin = one
//     coalesced 128B load of all 32 flags (no atomic serialization)
//   - weights LDS-resident (Wcomb slice 128K + Wbt 16K = 144K -> 1 blk/CU,
//     32 workers co-resident on XCD0's 32 CUs, claimed via XCC_ID ticket)
//   - prep kernels merged into one; Wfc transpose ticketed inside recur.
// Final GEMM keeps R8's LDS-transpose epilogue (aligned 512B runs kill the
// write-allocate RMW fetches diagnosed in R7).

#define VV 50257
#define VP 50304   // 786*64
#define TT 20
#define NWRK 32
#define NTILES 6288  // 786 * 8 transpose tiles

typedef __attribute__((ext_vector_type(4))) float f32x4;
typedef __attribute__((ext_vector_type(8))) short bf16x8;

#define MFMA(a,b,c) __builtin_amdgcn_mfma_f32_16x16x32_bf16((a),(b),(c),0,0,0)

__device__ __forceinline__ unsigned short f2bf(float f){
  union { float f; unsigned int u; } v; v.f = f;
  unsigned int u = v.u;
  return (unsigned short)((u + 0x7FFFu + ((u >> 16) & 1u)) >> 16);
}
__device__ __forceinline__ float sigf(float x){ return 1.f/(1.f + expf(-x)); }

__device__ __forceinline__ void gload_lds16(const unsigned short* g, unsigned short* l){
  __builtin_amdgcn_global_load_lds(
      (const __attribute__((address_space(1))) unsigned int*)g,
      (__attribute__((address_space(3))) unsigned int*)l, 16, 0, 0);
}

// ---- XCD0-L2-local accessors (sc0 = bypass L1 only; all workers share L2) ----
__device__ __forceinline__ void l2_load16(bf16x8* d, const unsigned short* p){
  asm volatile("global_load_dwordx4 %0, %1, off sc0" : "=v"(*d) : "v"(p));
}
__device__ __forceinline__ void l2_store2(unsigned short* p, unsigned short v){
  asm volatile("global_store_short %0, %1, off sc0" :: "v"(p), "v"(v) : "memory");
}

// flag barrier among the NWRK same-XCD workers
__device__ __forceinline__ void gbar(unsigned int* flags, int widx, unsigned target){
  asm volatile("s_waitcnt vmcnt(0)" ::: "memory");   // drain data stores to L2
  __syncthreads();
  if(threadIdx.x == 0){
    asm volatile("global_store_dword %0, %1, off sc0 sc1"
                 :: "v"(flags + widx), "v"(target) : "memory");
  }
  if(threadIdx.x < 64){
    const unsigned int* p = flags + (threadIdx.x & 31);
    for(;;){
      unsigned v;
      asm volatile("global_load_dword %0, %1, off sc0 sc1\n\ts_waitcnt vmcnt(0)"
                   : "=v"(v) : "v"(p) : "memory");
      if(__all((int)(v >= target))) break;
      __builtin_amdgcn_s_sleep(1);
    }
  }
  __syncthreads();
}

// ---------- merged prep kernel ----------
// blocks [0,2048): cvt_weights | [2048,2112): Wbeta transpose | [2112,3392):
// build_emb | [3392,3456): init h0/c0
__global__ __launch_bounds__(256) void prep(const float* __restrict__ Wih,
    const float* __restrict__ Whh, unsigned short* __restrict__ Wcomb,
    unsigned short* __restrict__ We,
    const float* __restrict__ Wbeta, unsigned short* __restrict__ Wbt,
    const float* __restrict__ feat, const float* __restrict__ emb,
    const int* __restrict__ cap, unsigned short* __restrict__ EmbMat,
    const float* __restrict__ Whi, const float* __restrict__ bhi,
    const float* __restrict__ Wci, const float* __restrict__ bci,
    unsigned short* __restrict__ xbuf, float* __restrict__ cbuf){
  __shared__ float tile[64][65];
  const int blk = blockIdx.x, tid = threadIdx.x;
  if(blk < 2048){
    int j = blk;
    for(int q=0;q<4;q++){ int k = tid + 256*q;
      float v = (k < 512) ? Whh[j*512 + k] : Wih[j*1024 + k];
      Wcomb[(size_t)j*1024 + k] = f2bf(v); }
    for(int q=0;q<2;q++){ int k = tid + 256*q;
      We[(size_t)j*512 + k] = f2bf(Wih[j*1024 + k]); }
  } else if(blk < 2112){
    int tb = blk - 2048;
    int c0 = (tb & 7)*64, r0 = (tb >> 3)*64;
    int tx = tid & 63, ty = tid >> 6;
    for(int i=0;i<16;i++){
      int r = ty + i*4;
      tile[r][tx] = Wbeta[(size_t)(r0+r)*512 + c0 + tx];
    }
    __syncthreads();
    for(int i=0;i<16;i++){
      int cl = ty + i*4;
      Wbt[(size_t)(c0+cl)*512 + r0 + tx] = f2bf(tile[tx][cl]);
    }
  } else if(blk < 3392){
    int m = blk - 2112; int t = m >> 6, b = m & 63;
    const float* src = (t == 0) ? (feat + b*512) : (emb + (size_t)cap[b*19 + (t-1)]*512);
    for(int q=0;q<2;q++){ int k = tid + 256*q;
      EmbMat[(size_t)m*512 + k] = f2bf(src[k]); }
  } else {
    int b = blk - 3392;
    float ah0 = bhi[tid], ah1 = bhi[tid+256];
    float ac0 = bci[tid], ac1 = bci[tid+256];
    for(int k=0;k<512;k++){
      float f = feat[b*512 + k];
      ah0 += f * Whi[k*512 + tid];     ah1 += f * Whi[k*512 + tid + 256];
      ac0 += f * Wci[k*512 + tid];     ac1 += f * Wci[k*512 + tid + 256];
    }
    xbuf[b*512 + tid] = f2bf(ah0);  xbuf[b*512 + tid + 256] = f2bf(ah1);
    cbuf[b*512 + tid] = ac0;        cbuf[b*512 + tid + 256] = ac1;
  }
}

// ---------- 128x128 NT MFMA GEMM, K=512, global_load_lds staging ----------
// EPIL 0: E4[((m*512)+col)*4 + gate] = acc + bias1[n] + bias2[n]
// EPIL 1: out rows m = b*20+t; LDS-transpose epilogue with aligned 512B runs
template<int EPIL>
__global__ __launch_bounds__(256) void gemm2(const unsigned short* __restrict__ Abf,
    const unsigned short* __restrict__ Bbf, const float* __restrict__ bias1,
    const float* __restrict__ bias2, const int* __restrict__ lensp,
    float* __restrict__ Cout, int MT){
  __shared__ __align__(16) char smem[32768];
  unsigned short* As = (unsigned short*)smem;
  unsigned short* Bs = (unsigned short*)(smem + 16384);
  float* et = (float*)smem;

  const int nwg = gridDim.x;
  const int id = blockIdx.x;
  const int q = nwg >> 3, rr = nwg & 7;
  const int xcd = id & 7, pos = id >> 3;
  const int work = (xcd < rr) ? (xcd*(q+1) + pos) : (rr*(q+1) + (xcd-rr)*q + pos);
  const int m0 = (work % MT) * 128;
  const int n0 = (work / MT) * 128;
  const int tid = threadIdx.x, lane = tid & 63, w = tid >> 6;
  const int wr = w >> 1, wc = w & 1;
  const int lrow = lane >> 3, lcol = (lane & 7) * 8;
  const int l15 = lane & 15, lhi = lane >> 4;

  f32x4 acc[4][4];
#pragma unroll
  for(int i=0;i<4;i++)
#pragma unroll
    for(int j=0;j<4;j++) acc[i][j] = f32x4{0.f,0.f,0.f,0.f};

  for(int k0=0;k0<512;k0+=64){
    __syncthreads();
#pragma unroll
    for(int i=0;i<4;i++){
      int c = w*4 + i;
      int row = c*8 + lrow;
      gload_lds16(Abf + (size_t)(m0+row)*512 + k0 + lcol, As + c*512);
      gload_lds16(Bbf + (size_t)(n0+row)*512 + k0 + lcol, Bs + c*512);
    }
    asm volatile("s_waitcnt vmcnt(0)" ::: "memory");
    __syncthreads();
#pragma unroll
    for(int kk=0;kk<64;kk+=32){
      bf16x8 af[4], bfv[4];
#pragma unroll
      for(int mf=0;mf<4;mf++)
        af[mf] = *(const bf16x8*)(As + (wr*64 + mf*16 + l15)*64 + kk + lhi*8);
#pragma unroll
      for(int nf=0;nf<4;nf++)
        bfv[nf] = *(const bf16x8*)(Bs + (wc*64 + nf*16 + l15)*64 + kk + lhi*8);
#pragma unroll
      for(int mf=0;mf<4;mf++)
#pragma unroll
        for(int nf=0;nf<4;nf++)
          acc[mf][nf] = MFMA(af[mf], bfv[nf], acc[mf][nf]);
    }
  }

  if constexpr (EPIL == 0){
#pragma unroll
    for(int mf=0;mf<4;mf++)
#pragma unroll
      for(int nf=0;nf<4;nf++){
        int n = n0 + wc*64 + nf*16 + l15;
#pragma unroll
        for(int r=0;r<4;r++){
          int m = m0 + wr*64 + mf*16 + lhi*4 + r;
          int gate = n >> 9, col = n & 511;
          Cout[((size_t)m*512 + col)*4 + gate] = acc[mf][nf][r] + bias1[n] + bias2[n];
        }
      }
  } else {
    const bool edge = (n0 + 128 > VV);
    for(int half=0; half<2; half++){
      __syncthreads();
      if(wr == half){
#pragma unroll
        for(int mf=0;mf<4;mf++)
#pragma unroll
          for(int nf=0;nf<4;nf++){
            int n = n0 + wc*64 + nf*16 + l15;
#pragma unroll
            for(int r=0;r<4;r++){
              int m = m0 + half*64 + mf*16 + lhi*4 + r;
              int b = m/20, tt = m%20;
              float v = (tt < lensp[b]) ? (acc[mf][nf][r] + bias1[n]) : 0.f;
              et[(mf*16 + lhi*4 + r)*128 + wc*64 + nf*16 + l15] = v;
            }
          }
      }
      __syncthreads();
#pragma unroll
      for(int qq=0;qq<8;qq++){
        int idx = tid + 256*qq;
        int row = idx >> 5, c4 = idx & 31;
        int m = m0 + half*64 + row;
        const float* er = et + row*128;
        if(!edge){
          size_t bdw = (size_t)m*VV + n0;
          int al = (int)((4 - (bdw & 3)) & 3);
          int chunks = (128 - al) >> 2;
          int tail = (128 - al) & 3;
          if(c4 < chunks){
            int s0 = al + c4*4;
            f32x4 v; v[0]=er[s0]; v[1]=er[s0+1]; v[2]=er[s0+2]; v[3]=er[s0+3];
            *(f32x4*)(Cout + bdw + s0) = v;
          }
          if(c4 < al) Cout[bdw + c4] = er[c4];
          if(c4 < tail){ int s1 = al + chunks*4 + c4; Cout[bdw + s1] = er[s1]; }
        } else {
#pragma unroll
          for(int i=0;i<4;i++){
            int cg = n0 + c4*4 + i;
            if(cg < VV) Cout[(size_t)m*VV + cg] = er[c4*4 + i];
          }
        }
      }
    }
  }
}

// ---------- single-XCD persistent recurrence + ticketed Wfc transpose ----------
// Worker w owns jj-slice [16w,16w+16). Per step:
//   ph1: 16 A-frags of h (sc0, direct to reg) -> beta(WbtLDS) + gates-h(WCbLDS)
//        -> awe store (sc0) -> flag barrier
//   ph2: 16 A-frags of awe -> gates-awe -> LSTM (E4, c in reg) -> h store (sc0)
//        + hs store (plain) -> flag barrier
// LDS: WCb [64][1024]swz 128K @0, WBb [16][512]swz 16K @131072 (144K total).
__global__ __launch_bounds__(256) void recur(
    const unsigned short* __restrict__ Wcomb,  // [2048][1024] bf16
    const unsigned short* __restrict__ Wbt,    // [512][512] bf16 (W_beta^T)
    const float* __restrict__ bbeta,
    const float* __restrict__ feat,            // [64][512] f32
    const float* __restrict__ E4,              // [(t*64+b)*512+j][4] f32 gate-minor
    const float* __restrict__ c0,
    const int* __restrict__ lens,
    unsigned short* xbuf,                      // [64][512] bf16 h (single buffer)
    unsigned short* awbuf,                     // [64][512] bf16 awe
    unsigned short* __restrict__ hs,           // [(b*20+t)][512] bf16
    unsigned int* ctrs,                        // [0]=worker tk, [16]=tp tk, [32..63]=flags
    const float* __restrict__ Wfc, unsigned short* __restrict__ Wfct){
  extern __shared__ char LDS[];
  char* WCb = LDS;            // 131072
  char* WBb = LDS + 131072;   // 16384
  int* lsh = (int*)LDS;
  const int tid = threadIdx.x;

  // ---- role assignment ----
  if(tid == 0){
    unsigned xcc = 99;
    asm volatile("s_getreg_b32 %0, hwreg(HW_REG_XCC_ID)" : "=s"(xcc));
    unsigned my = 0xffffffffu;
    if(xcc == 0) my = atomicAdd(&ctrs[0], 1u);
    lsh[0] = (my < NWRK) ? 1 : 0;
    lsh[1] = (int)my;
  }
  __syncthreads();
  const int iswork = lsh[0];
  const int widx = lsh[1];
  __syncthreads();

  if(!iswork){
    // ---- Wfc transpose via ticket ----
    float (*tile)[65] = (float(*)[65])LDS;
    int tx = tid & 63, ty = tid >> 6;
    for(;;){
      __syncthreads();
      if(tid == 0) lsh[0] = (int)atomicAdd(&ctrs[16], 1u);
      __syncthreads();
      int tb = lsh[0];
      __syncthreads();
      if(tb >= NTILES) return;
      int c0t = (tb % 786)*64, r0 = (tb / 786)*64;
      for(int i=0;i<16;i++){
        int r = ty + i*4; int sc = c0t + tx;
        tile[r][tx] = (sc < VV) ? Wfc[(size_t)(r0+r)*VV + sc] : 0.f;
      }
      __syncthreads();
      for(int i=0;i<16;i++){
        int cl = ty + i*4;
        Wfct[(size_t)(c0t+cl)*512 + r0 + tx] = f2bf(tile[tx][cl]);
      }
    }
  }

  // ---- worker ----
  const int lane = tid & 63, w = tid >> 6;
  const int l15 = lane & 15, lhi = lane >> 4;
  const int jj0 = widx * 16;
  const int jj = jj0 + l15;
  const int arow = w*16 + l15;
  unsigned int* flags = &ctrs[32];

  // stage Wcomb slice [64 gr][1024], gr = gate*16+rl <- global row gate*512+jj0+rl
  for(int cid = tid; cid < 8192; cid += 256){
    int gr = cid >> 7, cc = cid & 127;
    size_t g = (size_t)(gr >> 4)*512 + jj0 + (gr & 15);
    bf16x8 v = *(const bf16x8*)(Wcomb + g*1024 + cc*8);
    *(bf16x8*)(WCb + gr*2048 + ((cc*16) ^ ((gr & 7) << 4))) = v;
  }
  // stage Wbt slice [16][512] <- rows jj0..jj0+15
  for(int cid = tid; cid < 1024; cid += 256){
    int r = cid >> 6, cc = cid & 63;
    bf16x8 v = *(const bf16x8*)(Wbt + (size_t)(jj0 + r)*512 + cc*8);
    *(bf16x8*)(WBb + r*1024 + ((cc*16) ^ ((r & 7) << 4))) = v;
  }

  float c_reg[4], fe[4]; int ln[4]; unsigned short hold[4];
#pragma unroll
  for(int r=0;r<4;r++){
    int b = w*16 + lhi*4 + r;
    c_reg[r] = c0[b*512 + jj];
    fe[r]    = feat[b*512 + jj];
    ln[r]    = lens[b];
    hold[r]  = xbuf[b*512 + jj];     // plain: pre-step-0 value, raced by nobody yet
  }
  const float bb = bbeta[jj];
  const unsigned short* pAx = xbuf  + (size_t)arow*512 + lhi*8;
  const unsigned short* pAw = awbuf + (size_t)arow*512 + lhi*8;
  __syncthreads();

  for(int t=0;t<TT;t++){
    // ---- phase 1: h -> beta + gates-h ----
    bf16x8 a[16];
#pragma unroll
    for(int i=0;i<16;i++) l2_load16(&a[i], pAx + i*32);
    asm volatile("s_waitcnt vmcnt(0)" ::: "memory");
    __builtin_amdgcn_sched_barrier(0);

    f32x4 acca = f32x4{0.f,0.f,0.f,0.f};
    f32x4 accg[4];
#pragma unroll
    for(int i=0;i<4;i++) accg[i] = f32x4{0.f,0.f,0.f,0.f};
#pragma unroll
    for(int i=0;i<16;i++){
      int kb2 = i*64 + lhi*16;       // byte offset of element 2k within 1024B half
      bf16x8 wb = *(const bf16x8*)(WBb + l15*1024 + (kb2 ^ ((l15 & 7) << 4)));
      acca = MFMA(a[i], wb, acca);
#pragma unroll
      for(int nf=0; nf<4; nf++){
        int gr = nf*16 + l15;
        bf16x8 wg = *(const bf16x8*)(WCb + gr*2048 + (kb2 ^ ((gr & 7) << 4)));
        accg[nf] = MFMA(a[i], wg, accg[nf]);
      }
    }
#pragma unroll
    for(int r=0;r<4;r++){
      int b = w*16 + lhi*4 + r;
      float g = sigf(acca[r] + bb);
      l2_store2(awbuf + b*512 + jj, f2bf(g * fe[r]));
    }
    gbar(flags, widx, (unsigned)(2*t+1));

    // ---- phase 2: awe -> gates-awe ----
    f32x4 e4v[4];
#pragma unroll
    for(int r=0;r<4;r++){
      int b = w*16 + lhi*4 + r;
      e4v[r] = *(const f32x4*)(E4 + (((size_t)(t*64 + b))*512 + jj)*4);
    }
#pragma unroll
    for(int i=0;i<16;i++) l2_load16(&a[i], pAw + i*32);
    asm volatile("s_waitcnt vmcnt(0)" ::: "memory");
    __builtin_amdgcn_sched_barrier(0);
#pragma unroll
    for(int i=0;i<16;i++){
      int kb2 = 1024 + i*64 + lhi*16;
#pragma unroll
      for(int nf=0; nf<4; nf++){
        int gr = nf*16 + l15;
        bf16x8 wg = *(const bf16x8*)(WCb + gr*2048 + (kb2 ^ ((gr & 7) << 4)));
        accg[nf] = MFMA(a[i], wg, accg[nf]);
      }
    }

    // ---- fused LSTM epilogue ----
#pragma unroll
    for(int r=0;r<4;r++){
      int b = w*16 + lhi*4 + r;
      float iv = sigf(accg[0][r] + e4v[r][0]);
      float fv = sigf(accg[1][r] + e4v[r][1]);
      float gv = tanhf(accg[2][r] + e4v[r][2]);
      float ov = sigf(accg[3][r] + e4v[r][3]);
      float cn = fv*c_reg[r] + iv*gv;
      float hn = ov * tanhf(cn);
      bool valid = t < ln[r];
      if(valid) c_reg[r] = cn;
      unsigned short hb = valid ? f2bf(hn) : hold[r];
      hold[r] = hb;
      hs[((size_t)(b*20 + t))*512 + jj] = hb;
      l2_store2(xbuf + b*512 + jj, hb);
    }
    if(t < TT-1) gbar(flags, widx, (unsigned)(2*t+2));
  }
}

// ---------- launcher ----------
extern "C" void kernel_launch(void* const* d_in, const int* in_sizes, int n_in,
                              void* d_out, int out_size, void* d_ws, size_t ws_size,
                              hipStream_t stream){
  const float* feat  = (const float*)d_in[0];
  const int*   cap   = (const int*)  d_in[1];
  const int*   lens  = (const int*)  d_in[2];
  const float* emb   = (const float*)d_in[3];
  const float* Wih   = (const float*)d_in[4];
  const float* Whh   = (const float*)d_in[5];
  const float* bih   = (const float*)d_in[6];
  const float* bhh   = (const float*)d_in[7];
  // d_in[8..13]: attention weights -- dead (enc seq len == 1)
  const float* Whi   = (const float*)d_in[14];
  const float* bhi   = (const float*)d_in[15];
  const float* Wci   = (const float*)d_in[16];
  const float* bci   = (const float*)d_in[17];
  const float* Wbeta = (const float*)d_in[18];
  const float* bbeta = (const float*)d_in[19];
  const float* Wfc   = (const float*)d_in[20];
  const float* bfc   = (const float*)d_in[21];
  float* out = (float*)d_out;

  char* ws = (char*)d_ws;
  size_t off = 0;
  auto alloc = [&](size_t bytes)->void*{
    void* p = ws + off; off += (bytes + 1023) & ~(size_t)1023; return p; };
  unsigned short* Wcomb  = (unsigned short*)alloc((size_t)2048*1024*2);
  unsigned short* We     = (unsigned short*)alloc((size_t)2048*512*2);
  unsigned short* Wbt    = (unsigned short*)alloc((size_t)512*512*2);
  unsigned short* Wfct   = (unsigned short*)alloc((size_t)VP*512*2);
  unsigned short* EmbMat = (unsigned short*)alloc((size_t)1280*512*2);
  float*          E4     = (float*)alloc((size_t)1280*2048*4);
  unsigned short* xbuf   = (unsigned short*)alloc((size_t)64*512*2);
  unsigned short* awbuf  = (unsigned short*)alloc((size_t)64*512*2);
  float*          cbuf   = (float*)alloc((size_t)64*512*4);
  unsigned short* hs     = (unsigned short*)alloc((size_t)1280*512*2);
  unsigned int*   ctrs   = (unsigned int*)alloc(256);

  static_cast<void>(hipFuncSetAttribute((const void*)recur,
      hipFuncAttributeMaxDynamicSharedMemorySize, 147456));

  hipMemsetAsync(ctrs, 0, 256, stream);

  // merged prep: cvt_weights | Wbeta^T | embeddings | h0/c0
  prep<<<3456, 256, 0, stream>>>(Wih, Whh, Wcomb, We, Wbeta, Wbt, feat, emb,
                                 cap, EmbMat, Whi, bhi, Wci, bci, xbuf, cbuf);

  // E4 = emb-part of gates + b_ih + b_hh (gate-minor): M=1280, N=2048, K=512
  gemm2<0><<<160, 256, 0, stream>>>(EmbMat, We, bih, bhh, nullptr, E4, 10);

  // single-XCD recurrence + ticketed Wfc transpose
  recur<<<2080, 256, 147456, stream>>>(Wcomb, Wbt, bbeta, feat, E4, cbuf, lens,
                                       xbuf, awbuf, hs, ctrs, Wfc, Wfct);

  // preds: out[m = b*20+t][n] = mask ? hs @ Wfc + b_fc : 0 ; M=1280, N=50304, K=512
  gemm2<1><<<3930, 256, 0, stream>>>(hs, Wfct, bfc, nullptr, lens, out, 10);
}